// Round 10
// baseline (141.058 us; speedup 1.0000x reference)
//
#include <hip/hip_runtime.h>
#include <math.h>

// Single-head causal attention, MFMA bf16 pipeline (R10: transposed attn).
//   x:[8,2048,1024] f32, Wq/Wk/Wv:[1024,64] f32, zero_mask:[8,2048] i32
//   out:[8,2048,64] f32
// wcvt: Wt[192][1024] bf16 (B-operand layout)
// qkv : R9 structure (1024 blocks, X dbuf + W dbuf DMA, 40 KB, 4 blocks/CU)
// attn: TRANSPOSED flash: S^T = K Q^T (swapped MFMA operands). The S^T
//       C-frag (col=l15=q, row=quad*4+r=key) is directly a B-operand frag
//       for a 16-key PV slice -> P never goes through LDS: exp/mask/pack
//       in-register, O^T = V^T P^T via zero-padded 16x16x32 MFMA
//       (K=16 slice embedded at j=0..3 of both operands). Split-K of 8
//       tiles, grid (8,64,4); no-max softmax (scores tiny) is additive.
// comb: rows >= 512 sum ns=ceil(nkt/8) in {2..4} partials, normalize, zmask.
//
// MFMA 16x16x32 layouts (HW-verified):
//   A[m][k]: m = lane&15, k = (lane>>4)*8 + j
//   B[k][n]: n = lane&15, k = (lane>>4)*8 + j
//   C/D:     col = lane&15, row = (lane>>4)*4 + reg
//
// Swizzles (reader applies same XOR as the DMA source permutation):
//   64-bf16 row = 8 granules of 16B: slot = g ^ (row & 7)
//   64-fp32 row = 16 granules:       slot = g ^ (row & 15)

#define B_ 8
#define C_ 2048
#define E_ 1024
#define H_ 64
#define SCALE 0.02209708691207961f  // 2048^-0.5

typedef __attribute__((ext_vector_type(8))) short short8;
typedef __attribute__((ext_vector_type(4))) float floatx4;

union BF8 { short8 s8; unsigned int u[4]; };

static __device__ __forceinline__ unsigned int pack_bf2(float lo, float hi) {
    unsigned int a = __builtin_bit_cast(unsigned int, lo);
    unsigned int b = __builtin_bit_cast(unsigned int, hi);
    return (a >> 16) | (b & 0xFFFF0000u);
}
static __device__ __forceinline__ unsigned short f2bf(float f) {
    return (unsigned short)(__builtin_bit_cast(unsigned int, f) >> 16);
}
static __device__ __forceinline__ void load_lds16(const void* g, void* l) {
    __builtin_amdgcn_global_load_lds(
        (const __attribute__((address_space(1))) void*)g,
        (__attribute__((address_space(3))) void*)l, 16, 0, 0);
}

// ---------------------------------------------------------------------------
// Wt[n=192][k=1024] bf16 from Wq/Wk/Wv[k][64] f32. 48 blocks.
// ---------------------------------------------------------------------------
__global__ __launch_bounds__(256) void wcvt_kernel(
    const float* __restrict__ Wq, const float* __restrict__ Wk,
    const float* __restrict__ Wv, unsigned short* __restrict__ wt)
{
    __shared__ float lds[64][68];
    const int bid = (int)blockIdx.x;
    const int m = bid >> 4, kt = bid & 15, k0 = kt * 64;
    const float* W = (m == 0) ? Wq : (m == 1) ? Wk : Wv;
    const int t = (int)threadIdx.x;
#pragma unroll
    for (int j = 0; j < 4; j++) {
        int idx4 = j * 256 + t;
        int row = idx4 >> 4, c4 = idx4 & 15;
        float4 v = *(const float4*)(W + (size_t)(k0 + row) * 64 + c4 * 4);
        *(float4*)&lds[row][c4 * 4] = v;
    }
    __syncthreads();
#pragma unroll
    for (int j = 0; j < 2; j++) {
        int g = j * 256 + t;
        int n = g >> 3, kk = (g & 7) * 8;
        unsigned int o[4];
#pragma unroll
        for (int i = 0; i < 4; i++)
            o[i] = pack_bf2(lds[kk + 2 * i][n], lds[kk + 2 * i + 1][n]);
        *(uint4*)(wt + (size_t)(m * 64 + n) * 1024 + k0 + kk) =
            make_uint4(o[0], o[1], o[2], o[3]);
    }
}

// ---------------------------------------------------------------------------
// QKV: M=16384, N=192, K=1024. Grid (512 rowtiles, 2 colhalves), 256 thr.
// Block: 32 rows x 96 cols. Wave w: rows (w&1)*16, cols (w>>1)*48 (3 tiles).
// LDS 40 KB (X dbuf 16 KB + W dbuf 24 KB) -> 4 blocks/CU.  [R9, unchanged]
// ---------------------------------------------------------------------------
__global__ __launch_bounds__(256, 4) void qkv_kernel(
    const float* __restrict__ X, const unsigned short* __restrict__ wt,
    unsigned short* __restrict__ qg, unsigned short* __restrict__ kg,
    unsigned short* __restrict__ vtile)
{
    __shared__ __align__(16) unsigned char smem[2 * 8192 + 2 * 12288];
    unsigned short* vstage = (unsigned short*)smem;   // 5 KB alias, post-loop

    const int t = (int)threadIdx.x;
    const int w = t >> 6, lane = t & 63;
    const int l15 = lane & 15, quad = lane >> 4;
    const int r0 = (int)blockIdx.x * 32;
    const int ch = (int)blockIdx.y;            // col half: W rows ch*96..+95
    const int rbase = (w & 1) * 16;
    const int nloc0 = (w >> 1) * 48;

    const int wrow_off = lane >> 3, wgs = lane & 7;

    floatx4 acc[3];
#pragma unroll
    for (int j = 0; j < 3; j++) acc[j] = (floatx4){0.f, 0.f, 0.f, 0.f};

#define XBUF(q) (smem + (q) * 8192)
#define WBUF(q) (smem + 16384 + (q) * 12288)
#define STAGE_X(c, q) do {                                                   \
        _Pragma("unroll")                                                    \
        for (int j = 0; j < 2; j++) {                                        \
            const int gi = w * 128 + j * 64 + lane;                          \
            const int row = gi >> 4;                                         \
            const int g = (gi & 15) ^ (row & 15);                            \
            load_lds16(X + (size_t)(r0 + row) * E_ + (c) * 64 + g * 4,       \
                       XBUF(q) + (w * 128 + j * 64) * 16);                   \
        }                                                                    \
    } while (0)
#define STAGE_W(c, q) do {                                                   \
        _Pragma("unroll")                                                    \
        for (int j = 0; j < 3; j++) {                                        \
            const int region = w * 3 + j;                                    \
            const int nloc = region * 8 + wrow_off;                          \
            const int gsrc = wgs ^ (nloc & 7);                               \
            load_lds16(wt + (size_t)(ch * 96 + nloc) * 1024 + (c) * 64       \
                          + gsrc * 8,                                        \
                       WBUF(q) + region * 1024);                             \
        }                                                                    \
    } while (0)

    STAGE_X(0, 0);
    STAGE_W(0, 0);

#pragma unroll
    for (int c = 0; c < 16; c++) {
        __syncthreads();   // drains DMA issued last iter (vmcnt(0) structural)
        if (c + 1 < 16) {
            STAGE_X(c + 1, (c + 1) & 1);
            STAGE_W(c + 1, (c + 1) & 1);
        }
        const float4* xc = (const float4*)XBUF(c & 1);
        const unsigned short* wc = (const unsigned short*)WBUF(c & 1);

#pragma unroll
        for (int ks = 0; ks < 2; ks++) {
            const int g0 = ks * 8 + quad * 2;
            const float4* xrow = xc + (rbase + l15) * 16;
            float4 f0 = xrow[g0 ^ l15];
            float4 f1 = xrow[(g0 + 1) ^ l15];
            BF8 a;
            a.u[0] = pack_bf2(f0.x, f0.y);
            a.u[1] = pack_bf2(f0.z, f0.w);
            a.u[2] = pack_bf2(f1.x, f1.y);
            a.u[3] = pack_bf2(f1.z, f1.w);
#pragma unroll
            for (int nt = 0; nt < 3; nt++) {
                const int nloc = nloc0 + nt * 16 + l15;
                const int slot = (ks * 4 + quad) ^ (nloc & 7);
                short8 bfr = *(const short8*)(wc + nloc * 64 + slot * 8);
                acc[nt] = __builtin_amdgcn_mfma_f32_16x16x32_bf16(
                    a.s8, bfr, acc[nt], 0, 0, 0);
            }
        }
    }
#undef STAGE_X
#undef STAGE_W
#undef XBUF
#undef WBUF

    const int bb = r0 >> 11;
    const int keybase = r0 & 2047;
    const int rowl0 = rbase + quad * 4;
    __syncthreads();   // all LDS reads done; safe to alias vstage
#pragma unroll
    for (int nt = 0; nt < 3; nt++) {
        const int n = ch * 96 + nloc0 + nt * 16 + l15;
        if (n < 64) {
#pragma unroll
            for (int r = 0; r < 4; r++)
                qg[(size_t)(r0 + rowl0 + r) * 64 + n] = f2bf(acc[nt][r] * SCALE);
        } else if (n < 128) {
#pragma unroll
            for (int r = 0; r < 4; r++)
                kg[(size_t)(r0 + rowl0 + r) * 64 + (n - 64)] = f2bf(acc[nt][r]);
        } else {
            const int h = n - 128;
            *(unsigned int*)&vstage[h * 40 + rowl0] =
                pack_bf2(acc[nt][0], acc[nt][1]);
            *(unsigned int*)&vstage[h * 40 + rowl0 + 2] =
                pack_bf2(acc[nt][2], acc[nt][3]);
        }
    }
    if (ch == 1) {   // block-uniform branch; only ch=1 blocks hold V
        __syncthreads();
        const int h = t >> 2, part = t & 3;
        uint4 v = *(const uint4*)&vstage[h * 40 + part * 8];
        *(uint4*)(vtile + ((size_t)(bb * 32 + (keybase >> 6)) * 64 + h) * 64
                  + (keybase & 63) + part * 8) = v;
    }
}

// ---------------------------------------------------------------------------
// Attention split-K, TRANSPOSED. Grid (8, 64, 4); 128 thr (2 waves);
// 32 q-rows/block (wave w: q = qlo + l15, qlo = q0 + w*16).
// S^T = K Q^T; P^T stays in registers; O^T = V^T P^T via zero-padded
// 16x16x32 MFMA per 16-key slice. K/V dbuf via swizzled DMA, 32 KB LDS.
// ---------------------------------------------------------------------------
__global__ __launch_bounds__(128, 3) void attn_kernel(
    const unsigned short* __restrict__ qg, const unsigned short* __restrict__ kg,
    const unsigned short* __restrict__ vtile, const int* __restrict__ zmask,
    float* __restrict__ opart, float* __restrict__ lpart,
    float* __restrict__ out)
{
    __shared__ unsigned short Klds[2][64 * 64];  // swizzled [key][64h]
    __shared__ unsigned short Vlds[2][64 * 64];  // swizzled [h][64key]

    const int t = (int)threadIdx.x;
    const int w = t >> 6, lane = t & 63;
    const int l15 = lane & 15, quad = lane >> 4;
    const int b = (int)blockIdx.x;
    const int qt = (int)blockIdx.y;
    const int z = (int)blockIdx.z;
    const int q0 = qt * 32;
    const int nkt = (q0 >> 6) + 1;
    const int t0 = z * 8;
    const int t1 = (t0 + 8 < nkt) ? (t0 + 8) : nkt;
    if (t0 >= t1) return;
    const int ns = (nkt + 7) >> 3;

    const int qlo = q0 + w * 16;
    const int myq = qlo + l15;                 // this lane's q row
    const int srow_off = lane >> 3, sgs = lane & 7;

    // Q as B-operand of S^T (n = l15 = q, k = quad*8+j); scale pre-folded
    short8 qfr[2];
#pragma unroll
    for (int kc = 0; kc < 2; kc++)
        qfr[kc] = *(const short8*)(qg + ((size_t)b * C_ + qlo + l15) * 64
                                   + kc * 32 + quad * 8);

    floatx4 accO[4];   // O^T: accO[ht], col=l15=q, row=quad*4+r = local h
#pragma unroll
    for (int i = 0; i < 4; i++) accO[i] = (floatx4){0.f, 0.f, 0.f, 0.f};
    float lsum = 0.f;

    // stage tile t0 into buf 0
#pragma unroll
    for (int j = 0; j < 4; j++) {
        const int region = w * 4 + j;
        const int row = region * 8 + srow_off;
        const int gsrc = sgs ^ (row & 7);
        load_lds16(kg + ((size_t)b * C_ + t0 * 64 + row) * 64 + gsrc * 8,
                   &Klds[0][region * 512]);
        load_lds16(vtile + (((size_t)b * 32 + t0) * 64 + row) * 64 + gsrc * 8,
                   &Vlds[0][region * 512]);
    }

    int buf = 0;
    for (int kt = t0; kt < t1; kt++) {
        __syncthreads();
        if (kt + 1 < t1) {
            const int k0n = (kt + 1) * 64;
#pragma unroll
            for (int j = 0; j < 4; j++) {
                const int region = w * 4 + j;
                const int row = region * 8 + srow_off;
                const int gsrc = sgs ^ (row & 7);
                load_lds16(kg + ((size_t)b * C_ + k0n + row) * 64 + gsrc * 8,
                           &Klds[buf ^ 1][region * 512]);
                load_lds16(vtile + (((size_t)b * 32 + kt + 1) * 64 + row) * 64 + gsrc * 8,
                           &Vlds[buf ^ 1][region * 512]);
            }
        }

        // S^T = K Q^T  (A = K rows, B = Q): col=l15=q, row=quad*4+r=key
        floatx4 s[4];
#pragma unroll
        for (int nt = 0; nt < 4; nt++) {
            const int row = nt * 16 + l15;
            short8 kf0 = *(const short8*)&Klds[buf][row * 64 + ((quad) ^ (row & 7)) * 8];
            short8 kf1 = *(const short8*)&Klds[buf][row * 64 + ((4 + quad) ^ (row & 7)) * 8];
            floatx4 zz = (floatx4){0.f, 0.f, 0.f, 0.f};
            zz = __builtin_amdgcn_mfma_f32_16x16x32_bf16(kf0, qfr[0], zz, 0, 0, 0);
            s[nt] = __builtin_amdgcn_mfma_f32_16x16x32_bf16(kf1, qfr[1], zz, 0, 0, 0);
        }

        // P^T = exp(S^T) in-register; mask diagonal tile; pack bf16; row sums
        unsigned int pb[4][2];   // per nt: 4 bf16 (keys quad*4+0..3)
#pragma unroll
        for (int nt = 0; nt < 4; nt++) {
            float pr[4];
#pragma unroll
            for (int r = 0; r < 4; r++) pr[r] = __expf(s[nt][r]);
            if (kt == nkt - 1) {
#pragma unroll
                for (int r = 0; r < 4; r++) {
                    const int key = kt * 64 + nt * 16 + quad * 4 + r;
                    if (key > myq) pr[r] = 0.f;
                }
            }
#pragma unroll
            for (int r = 0; r < 4; r++) lsum += pr[r];
            pb[nt][0] = pack_bf2(pr[0], pr[1]);
            pb[nt][1] = pack_bf2(pr[2], pr[3]);
        }

        // O^T += V^T P^T: per (nt,ht) one 16x16x32 MFMA with the K=16 slice
        // embedded at j=0..3 (both operands zero-padded at j=4..7).
#pragma unroll
        for (int nt = 0; nt < 4; nt++) {
            BF8 pbf;
            pbf.u[0] = pb[nt][0];
            pbf.u[1] = pb[nt][1];
            pbf.u[2] = 0;
            pbf.u[3] = 0;
#pragma unroll
            for (int ht = 0; ht < 4; ht++) {
                const int row = ht * 16 + l15;                 // h row
                const int g8 = 2 * nt + (quad >> 1);           // 16B granule
                const int slot = g8 ^ (row & 7);
                const unsigned short* vp =
                    &Vlds[buf][row * 64 + slot * 8 + (quad & 1) * 4];
                uint2 vv = *(const uint2*)vp;                  // 4 bf16 keys
                BF8 vbf;
                vbf.u[0] = vv.x;
                vbf.u[1] = vv.y;
                vbf.u[2] = 0;
                vbf.u[3] = 0;
                accO[ht] = __builtin_amdgcn_mfma_f32_16x16x32_bf16(
                    vbf.s8, pbf.s8, accO[ht], 0, 0, 0);
            }
        }
        buf ^= 1;
    }

    // full row sum for q = l15: reduce across the 4 quads
    lsum += __shfl_xor(lsum, 16);
    lsum += __shfl_xor(lsum, 32);

    if (ns == 1) {
        const float inv = zmask[b * C_ + myq] ? 0.f : 1.0f / lsum;
#pragma unroll
        for (int ht = 0; ht < 4; ht++)
            *(float4*)(out + ((size_t)b * C_ + myq) * 64 + ht * 16 + quad * 4) =
                make_float4(accO[ht][0] * inv, accO[ht][1] * inv,
                            accO[ht][2] * inv, accO[ht][3] * inv);
    } else {
        // partials (myq >= 512): opart[z][b][q-512][h] unnormalized
        const int lrow = myq - 512;
        float* ob = opart + ((size_t)(z * 8 + b) * 1536 + lrow) * 64;
#pragma unroll
        for (int ht = 0; ht < 4; ht++)
            *(float4*)(ob + ht * 16 + quad * 4) =
                make_float4(accO[ht][0], accO[ht][1], accO[ht][2], accO[ht][3]);
        if (quad == 0)
            lpart[(size_t)(z * 8 + b) * 1536 + lrow] = lsum;
    }
}

// ---------------------------------------------------------------------------
// Combine rows >= 512: out = sum_z O_z / sum_z l_z, zmask applied.
// Grid (96, 8): 8 b x 1536 rows x 16 float4.
// ---------------------------------------------------------------------------
__global__ __launch_bounds__(256) void combine_kernel(
    const float* __restrict__ opart, const float* __restrict__ lpart,
    const int* __restrict__ zmask, float* __restrict__ out)
{
    const int b = (int)blockIdx.y;
    const int gid = (int)blockIdx.x * 256 + (int)threadIdx.x;  // 0..24575
    const int lrow = gid >> 4;         // 0..1535
    const int f4 = gid & 15;
    const int row = 512 + lrow;
    const int nkt = (row >> 6) + 1;
    const int ns = (nkt + 7) >> 3;     // 2..4

    float4 o = make_float4(0.f, 0.f, 0.f, 0.f);
    float l = 0.f;
    for (int zc = 0; zc < ns; zc++) {
        float4 p = *(const float4*)(opart
            + ((size_t)(zc * 8 + b) * 1536 + lrow) * 64 + f4 * 4);
        o.x += p.x; o.y += p.y; o.z += p.z; o.w += p.w;
        l += lpart[(size_t)(zc * 8 + b) * 1536 + lrow];
    }
    const float inv = zmask[b * C_ + row] ? 0.f : 1.0f / l;
    *(float4*)(out + (size_t)(b * C_ + row) * 64 + f4 * 4) =
        make_float4(o.x * inv, o.y * inv, o.z * inv, o.w * inv);
}

// ---------------------------------------------------------------------------
extern "C" void kernel_launch(void* const* d_in, const int* in_sizes, int n_in,
                              void* d_out, int out_size, void* d_ws, size_t ws_size,
                              hipStream_t stream) {
    const float* X  = (const float*)d_in[0];
    const float* Wq = (const float*)d_in[1];
    const float* Wk = (const float*)d_in[2];
    const float* Wv = (const float*)d_in[3];
    const int*   zm = (const int*)d_in[4];
    float* out = (float*)d_out;

    unsigned short* qg    = (unsigned short*)d_ws;               // 2 MB
    unsigned short* kg    = qg    + (size_t)B_ * C_ * H_;        // 2 MB
    unsigned short* vtile = kg    + (size_t)B_ * C_ * H_;        // 2 MB
    unsigned short* wt    = vtile + (size_t)B_ * C_ * H_;        // 384 KB
    float* opart = (float*)(wt + (size_t)192 * 1024);            // 12.6 MB
    float* lpart = opart + (size_t)4 * 8 * 1536 * 64;            // 192 KB

    wcvt_kernel<<<dim3(48), dim3(256), 0, stream>>>(Wq, Wk, Wv, wt);
    qkv_kernel<<<dim3(512, 2), dim3(256), 0, stream>>>(X, wt, qg, kg, vtile);
    attn_kernel<<<dim3(B_, 64, 4), dim3(128), 0, stream>>>(
        qg, kg, vtile, zm, opart, lpart, out);
    combine_kernel<<<dim3(96, B_), dim3(256), 0, stream>>>(opart, lpart, zm, out);
}